// Round 5
// baseline (244.459 us; speedup 1.0000x reference)
//
#include <hip/hip_runtime.h>
#include <math.h>

#define KDIM 64
#define TDIM 100
#define VDIM 10000
#define NV4  2500            // VDIM / 4
#define BLOCK 256
#define NWAVE (BLOCK / 64)
#define VPT 10               // NV4 / BLOCK rounded up
#define HALF 5
#define CHUNK 5
#define NCHUNK (TDIM / CHUNK)

#define INV1 (1.0f / (1.0f + 1e-6f))
#define INVD (1.0f / (0.005f + 1e-6f))
#define LOGD (-5.2983173665480363f)   // log(0.005f)

__device__ __forceinline__ float wave_red_sum(float v) {
#pragma unroll
    for (int m = 32; m >= 1; m >>= 1) v += __shfl_xor(v, m, 64);
    return v;
}

// barrier that does NOT drain vmcnt: prefetched global loads stay in flight.
// lgkmcnt(0) commits our ds_write of the reduction slot before the barrier.
__device__ __forceinline__ void lds_barrier() {
    asm volatile("s_waitcnt lgkmcnt(0)\n\ts_barrier" ::: "memory");
}

// beta + optional KL + exp-sum for one float4; updates bprev slot in place.
__device__ __forceinline__ void consume(const float4 m, const float4 l, const float4 e,
                                        float4& bp, const bool first, const bool skip_kl,
                                        float& klacc, float& lsum) {
    float4 b;
    b.x = fmaf(__expf(0.5f * l.x), e.x, m.x);
    b.y = fmaf(__expf(0.5f * l.y), e.y, m.y);
    b.z = fmaf(__expf(0.5f * l.z), e.z, m.z);
    b.w = fmaf(__expf(0.5f * l.w), e.w, m.w);
    if (!skip_kl) {
        if (first) {
            klacc += (__expf(l.x) + m.x * m.x) * INV1 - 1.0f - l.x;
            klacc += (__expf(l.y) + m.y * m.y) * INV1 - 1.0f - l.y;
            klacc += (__expf(l.z) + m.z * m.z) * INV1 - 1.0f - l.z;
            klacc += (__expf(l.w) + m.w * m.w) * INV1 - 1.0f - l.w;
        } else {
            const float dx = m.x - bp.x, dy = m.y - bp.y, dz = m.z - bp.z, dw = m.w - bp.w;
            klacc += (__expf(l.x) + dx * dx) * INVD - 1.0f + LOGD - l.x;
            klacc += (__expf(l.y) + dy * dy) * INVD - 1.0f + LOGD - l.y;
            klacc += (__expf(l.z) + dz * dz) * INVD - 1.0f + LOGD - l.z;
            klacc += (__expf(l.w) + dw * dw) * INVD - 1.0f + LOGD - l.w;
        }
    }
    bp = b;
    lsum += __expf(b.x) + __expf(b.y) + __expf(b.z) + __expf(b.w);
}

// KL step term only (forward handoff row): uses mu/lsq of row t, beta of t-1
__device__ __forceinline__ void kl_step(const float4 m, const float4 l,
                                        const float4 bp, float& klacc) {
    const float dx = m.x - bp.x, dy = m.y - bp.y, dz = m.z - bp.z, dw = m.w - bp.w;
    klacc += (__expf(l.x) + dx * dx) * INVD - 1.0f + LOGD - l.x;
    klacc += (__expf(l.y) + dy * dy) * INVD - 1.0f + LOGD - l.y;
    klacc += (__expf(l.z) + dz * dz) * INVD - 1.0f + LOGD - l.z;
    klacc += (__expf(l.w) + dw * dw) * INVD - 1.0f + LOGD - l.w;
}

__global__ __launch_bounds__(BLOCK, 2) void fused_beta_softmax_kl(
    const float* __restrict__ mu_q,   // [K, T, V]
    const float* __restrict__ lsq,    // [K, T, V]
    const float* __restrict__ eps,    // [T, K, V]
    float* __restrict__ out,          // [T, K, V]
    float* __restrict__ kl)           // scalar (pre-zeroed)
{
    __shared__ float red[2][NWAVE];
    __shared__ float kred[NWAVE];

    const int tid = threadIdx.x;
    const int bid = blockIdx.x;
    const int k   = bid / NCHUNK;
    const int c   = bid % NCHUNK;
    const int t0  = c * CHUNK;
    const int tend = t0 + CHUNK;
    const bool epi = (tend < TDIM);   // this block also computes KL term of row tend

    float4 bprev[VPT];
    float  klacc = 0.0f;
    float4 MA[HALF], LA[HALF], EA[HALF];   // half 0 (idx < 1280, never OOB)
    float4 MB[HALF], LB[HALF], EB[HALF];   // half 1 (guarded)

    // ---- prologue: issue both halves of row t0 ----
    {
        const size_t po = ((size_t)k * TDIM + t0) * VDIM;
        const size_t eo = ((size_t)t0 * KDIM + k) * VDIM;
        const float4* m4p = reinterpret_cast<const float4*>(mu_q + po);
        const float4* l4p = reinterpret_cast<const float4*>(lsq + po);
        const float4* e4p = reinterpret_cast<const float4*>(eps + eo);
#pragma unroll
        for (int jj = 0; jj < HALF; ++jj) {
            const int idx = tid + jj * BLOCK;
            MA[jj] = m4p[idx]; LA[jj] = l4p[idx]; EA[jj] = e4p[idx];
        }
#pragma unroll
        for (int jj = 0; jj < HALF; ++jj) {
            const int idx = tid + (HALF + jj) * BLOCK;
            if (idx < NV4) { MB[jj] = m4p[idx]; LB[jj] = l4p[idx]; EB[jj] = e4p[idx]; }
        }
    }

    // ---- main loop: invariant at top: both halves of row t are in flight ----
    for (int t = t0; t < tend; ++t) {
        const int  tn    = t + 1;
        const bool first = (t == 0);
        const bool skip  = (t == t0) && (t0 != 0);   // handoff: prev block owns this KL term
        float lsum = 0.0f;

        // consume half 0
#pragma unroll
        for (int jj = 0; jj < HALF; ++jj)
            consume(MA[jj], LA[jj], EA[jj], bprev[jj], first, skip, klacc, lsum);

        // refill A: next row's half 0, or epilogue mu/lsq of row tend
        if (tn < tend) {
            const size_t po = ((size_t)k * TDIM + tn) * VDIM;
            const size_t eo = ((size_t)tn * KDIM + k) * VDIM;
            const float4* m4p = reinterpret_cast<const float4*>(mu_q + po);
            const float4* l4p = reinterpret_cast<const float4*>(lsq + po);
            const float4* e4p = reinterpret_cast<const float4*>(eps + eo);
#pragma unroll
            for (int jj = 0; jj < HALF; ++jj) {
                const int idx = tid + jj * BLOCK;
                MA[jj] = m4p[idx]; LA[jj] = l4p[idx]; EA[jj] = e4p[idx];
            }
        } else if (epi) {
            const size_t po = ((size_t)k * TDIM + tend) * VDIM;
            const float4* m4p = reinterpret_cast<const float4*>(mu_q + po);
            const float4* l4p = reinterpret_cast<const float4*>(lsq + po);
#pragma unroll
            for (int jj = 0; jj < HALF; ++jj) {
                const int idx = tid + jj * BLOCK;
                MA[jj] = m4p[idx]; LA[jj] = l4p[idx];
            }
        }

        // consume half 1 (guarded)
#pragma unroll
        for (int jj = 0; jj < HALF; ++jj) {
            const int idx = tid + (HALF + jj) * BLOCK;
            if (idx < NV4)
                consume(MB[jj], LB[jj], EB[jj], bprev[HALF + jj], first, skip, klacc, lsum);
        }

        // refill B
        if (tn < tend) {
            const size_t po = ((size_t)k * TDIM + tn) * VDIM;
            const size_t eo = ((size_t)tn * KDIM + k) * VDIM;
            const float4* m4p = reinterpret_cast<const float4*>(mu_q + po);
            const float4* l4p = reinterpret_cast<const float4*>(lsq + po);
            const float4* e4p = reinterpret_cast<const float4*>(eps + eo);
#pragma unroll
            for (int jj = 0; jj < HALF; ++jj) {
                const int idx = tid + (HALF + jj) * BLOCK;
                if (idx < NV4) { MB[jj] = m4p[idx]; LB[jj] = l4p[idx]; EB[jj] = e4p[idx]; }
            }
        } else if (epi) {
            const size_t po = ((size_t)k * TDIM + tend) * VDIM;
            const float4* m4p = reinterpret_cast<const float4*>(mu_q + po);
            const float4* l4p = reinterpret_cast<const float4*>(lsq + po);
#pragma unroll
            for (int jj = 0; jj < HALF; ++jj) {
                const int idx = tid + (HALF + jj) * BLOCK;
                if (idx < NV4) { MB[jj] = m4p[idx]; LB[jj] = l4p[idx]; }
            }
        }

        // ---- exp-sum block reduction (vmcnt-preserving barrier) ----
        const int slot = t & 1;
        float ws = wave_red_sum(lsum);
        if ((tid & 63) == 0) red[slot][tid >> 6] = ws;
        lds_barrier();
        float rowsum = 0.0f;
#pragma unroll
        for (int w = 0; w < NWAVE; ++w) rowsum += red[slot][w];
        const float invs = 1.0f / rowsum;

        // ---- write softmax = exp(beta) * invs ----
        float4* o4p = reinterpret_cast<float4*>(out + ((size_t)t * KDIM + k) * VDIM);
#pragma unroll
        for (int j = 0; j < VPT; ++j) {
            const int idx = tid + j * BLOCK;
            if (idx < NV4) {
                const float4 b = bprev[j];
                float4 o;
                o.x = __expf(b.x) * invs;
                o.y = __expf(b.y) * invs;
                o.z = __expf(b.z) * invs;
                o.w = __expf(b.w) * invs;
                o4p[idx] = o;
            }
        }
    }

    // ---- forward-handoff KL for row tend (loads were prefetched in last iter) ----
    if (epi) {
#pragma unroll
        for (int jj = 0; jj < HALF; ++jj)
            kl_step(MA[jj], LA[jj], bprev[jj], klacc);
#pragma unroll
        for (int jj = 0; jj < HALF; ++jj) {
            const int idx = tid + (HALF + jj) * BLOCK;
            if (idx < NV4)
                kl_step(MB[jj], LB[jj], bprev[HALF + jj], klacc);
        }
    }

    // ---- KL block reduction + one atomic per block ----
    float wk = wave_red_sum(klacc);
    __syncthreads();
    if ((tid & 63) == 0) kred[tid >> 6] = wk;
    __syncthreads();
    if (tid == 0) {
        float tot = 0.0f;
#pragma unroll
        for (int w = 0; w < NWAVE; ++w) tot += kred[w];
        atomicAdd(kl, 0.5f * tot);
    }
}

extern "C" void kernel_launch(void* const* d_in, const int* in_sizes, int n_in,
                              void* d_out, int out_size, void* d_ws, size_t ws_size,
                              hipStream_t stream) {
    const float* mu_q = (const float*)d_in[0];  // [K,T,V]
    const float* lsq  = (const float*)d_in[1];  // [K,T,V]
    const float* eps  = (const float*)d_in[2];  // [T,K,V]
    float* out = (float*)d_out;                 // [T,K,V] softmax, then 1 float KL
    float* kl  = out + (size_t)TDIM * KDIM * VDIM;

    // zero the KL accumulator each launch (graph-capture-safe)
    hipMemsetAsync(kl, 0, sizeof(float), stream);

    dim3 grid(KDIM * NCHUNK);
    fused_beta_softmax_kl<<<grid, BLOCK, 0, stream>>>(mu_q, lsq, eps, out, kl);
}

// Round 6
// 228.124 us; speedup vs baseline: 1.0716x; 1.0716x over previous
//
#include <hip/hip_runtime.h>
#include <math.h>

#define KDIM 64
#define TDIM 100
#define VDIM 10000
#define NV4  2500            // VDIM / 4
#define BLOCK 512
#define NWAVE (BLOCK / 64)   // 8
#define VPT 5                // ceil(NV4 / BLOCK)
#define CHUNK 5
#define NCHUNK (TDIM / CHUNK)

#define INV1 (1.0f / (1.0f + 1e-6f))
#define INVD (1.0f / (0.005f + 1e-6f))
#define LOGD (-5.2983173665480363f)   // log(0.005f)

// guard: jj < VPT-1 rows are always in range (tid + 3*512 <= 2047 < 2500)
#define INRANGE(jj, idx) ((jj) < VPT - 1 || (idx) < NV4)

__device__ __forceinline__ float wave_red_sum(float v) {
#pragma unroll
    for (int m = 32; m >= 1; m >>= 1) v += __shfl_xor(v, m, 64);
    return v;
}

// barrier that does NOT drain vmcnt: stores/loads stay in flight.
// lgkmcnt(0) commits our ds_write of the reduction slot before the barrier.
__device__ __forceinline__ void lds_barrier() {
    asm volatile("s_waitcnt lgkmcnt(0)\n\ts_barrier" ::: "memory");
}

__global__ __launch_bounds__(BLOCK) void fused_beta_softmax_kl(
    const float* __restrict__ mu_q,   // [K, T, V]
    const float* __restrict__ lsq,    // [K, T, V]
    const float* __restrict__ eps,    // [T, K, V]
    float* __restrict__ out,          // [T, K, V]
    float* __restrict__ kl)           // scalar (pre-zeroed)
{
    __shared__ float4 bprev[NV4];     // 40 KB: beta of current row, thread-private slots
    __shared__ float red[2][NWAVE];
    __shared__ float kred[NWAVE];

    const int tid = threadIdx.x;
    const int bid = blockIdx.x;
    const int k   = bid / NCHUNK;
    const int c   = bid % NCHUNK;
    const int t0  = c * CHUNK;
    const int tend = t0 + CHUNK;
    const bool epi = (tend < TDIM);   // this block computes KL term of row tend too

    float klacc = 0.0f;
    float4 M[VPT], L[VPT], E[VPT];    // staging: 15 loads in flight

    for (int t = t0; t < tend; ++t) {
        const size_t po = ((size_t)k * TDIM + t) * VDIM;
        const size_t eo = ((size_t)t * KDIM + k) * VDIM;
        const float4* m4p = reinterpret_cast<const float4*>(mu_q + po);
        const float4* l4p = reinterpret_cast<const float4*>(lsq + po);
        const float4* e4p = reinterpret_cast<const float4*>(eps + eo);
        const bool first = (t == 0);
        const bool skip  = (t == t0) && (t0 != 0);   // prev block owns this KL term

        // ---- stage all 15 global loads ----
#pragma unroll
        for (int jj = 0; jj < VPT; ++jj) {
            const int idx = tid + jj * BLOCK;
            if (INRANGE(jj, idx)) { M[jj] = m4p[idx]; L[jj] = l4p[idx]; E[jj] = e4p[idx]; }
        }

        // ---- consume: beta -> LDS, KL vs old LDS beta, exp-sum ----
        float lsum = 0.0f;
#pragma unroll
        for (int jj = 0; jj < VPT; ++jj) {
            const int idx = tid + jj * BLOCK;
            if (INRANGE(jj, idx)) {
                const float4 m = M[jj], l = L[jj], e = E[jj];
                float4 b;
                b.x = fmaf(__expf(0.5f * l.x), e.x, m.x);
                b.y = fmaf(__expf(0.5f * l.y), e.y, m.y);
                b.z = fmaf(__expf(0.5f * l.z), e.z, m.z);
                b.w = fmaf(__expf(0.5f * l.w), e.w, m.w);
                if (first) {
                    klacc += (__expf(l.x) + m.x * m.x) * INV1 - 1.0f - l.x;
                    klacc += (__expf(l.y) + m.y * m.y) * INV1 - 1.0f - l.y;
                    klacc += (__expf(l.z) + m.z * m.z) * INV1 - 1.0f - l.z;
                    klacc += (__expf(l.w) + m.w * m.w) * INV1 - 1.0f - l.w;
                } else if (!skip) {
                    const float4 p = bprev[idx];
                    const float dx = m.x - p.x, dy = m.y - p.y,
                                dz = m.z - p.z, dw = m.w - p.w;
                    klacc += (__expf(l.x) + dx * dx) * INVD - 1.0f + LOGD - l.x;
                    klacc += (__expf(l.y) + dy * dy) * INVD - 1.0f + LOGD - l.y;
                    klacc += (__expf(l.z) + dz * dz) * INVD - 1.0f + LOGD - l.z;
                    klacc += (__expf(l.w) + dw * dw) * INVD - 1.0f + LOGD - l.w;
                }
                bprev[idx] = b;
                lsum += __expf(b.x) + __expf(b.y) + __expf(b.z) + __expf(b.w);
            }
        }

        // ---- exp-sum block reduction (vmcnt-preserving barrier) ----
        const int slot = t & 1;
        float ws = wave_red_sum(lsum);
        if ((tid & 63) == 0) red[slot][tid >> 6] = ws;
        lds_barrier();
        float rowsum = 0.0f;
#pragma unroll
        for (int w = 0; w < NWAVE; ++w) rowsum += red[slot][w];
        const float invs = 1.0f / rowsum;

        // ---- write softmax = exp(beta) * invs, beta re-read from LDS ----
        float4* o4p = reinterpret_cast<float4*>(out + ((size_t)t * KDIM + k) * VDIM);
#pragma unroll
        for (int jj = 0; jj < VPT; ++jj) {
            const int idx = tid + jj * BLOCK;
            if (INRANGE(jj, idx)) {
                const float4 b = bprev[idx];
                float4 o;
                o.x = __expf(b.x) * invs;
                o.y = __expf(b.y) * invs;
                o.z = __expf(b.z) * invs;
                o.w = __expf(b.w) * invs;
                o4p[idx] = o;
            }
        }
        // bprev slots are thread-private; red double-buffered -> one barrier/row
    }

    // ---- forward-handoff KL for row tend (mu/lsq only) ----
    if (epi) {
        const size_t po = ((size_t)k * TDIM + tend) * VDIM;
        const float4* m4p = reinterpret_cast<const float4*>(mu_q + po);
        const float4* l4p = reinterpret_cast<const float4*>(lsq + po);
#pragma unroll
        for (int jj = 0; jj < VPT; ++jj) {
            const int idx = tid + jj * BLOCK;
            if (INRANGE(jj, idx)) { M[jj] = m4p[idx]; L[jj] = l4p[idx]; }
        }
#pragma unroll
        for (int jj = 0; jj < VPT; ++jj) {
            const int idx = tid + jj * BLOCK;
            if (INRANGE(jj, idx)) {
                const float4 m = M[jj], l = L[jj];
                const float4 p = bprev[idx];
                const float dx = m.x - p.x, dy = m.y - p.y,
                            dz = m.z - p.z, dw = m.w - p.w;
                klacc += (__expf(l.x) + dx * dx) * INVD - 1.0f + LOGD - l.x;
                klacc += (__expf(l.y) + dy * dy) * INVD - 1.0f + LOGD - l.y;
                klacc += (__expf(l.z) + dz * dz) * INVD - 1.0f + LOGD - l.z;
                klacc += (__expf(l.w) + dw * dw) * INVD - 1.0f + LOGD - l.w;
            }
        }
    }

    // ---- KL block reduction + one atomic per block ----
    float wk = wave_red_sum(klacc);
    __syncthreads();
    if ((tid & 63) == 0) kred[tid >> 6] = wk;
    __syncthreads();
    if (tid == 0) {
        float tot = 0.0f;
#pragma unroll
        for (int w = 0; w < NWAVE; ++w) tot += kred[w];
        atomicAdd(kl, 0.5f * tot);
    }
}

extern "C" void kernel_launch(void* const* d_in, const int* in_sizes, int n_in,
                              void* d_out, int out_size, void* d_ws, size_t ws_size,
                              hipStream_t stream) {
    const float* mu_q = (const float*)d_in[0];  // [K,T,V]
    const float* lsq  = (const float*)d_in[1];  // [K,T,V]
    const float* eps  = (const float*)d_in[2];  // [T,K,V]
    float* out = (float*)d_out;                 // [T,K,V] softmax, then 1 float KL
    float* kl  = out + (size_t)TDIM * KDIM * VDIM;

    // zero the KL accumulator each launch (graph-capture-safe)
    hipMemsetAsync(kl, 0, sizeof(float), stream);

    dim3 grid(KDIM * NCHUNK);
    fused_beta_softmax_kl<<<grid, BLOCK, 0, stream>>>(mu_q, lsq, eps, out, kl);
}

// Round 8
// 201.195 us; speedup vs baseline: 1.2150x; 1.1338x over previous
//
#include <hip/hip_runtime.h>
#include <math.h>

#define KDIM 64
#define TDIM 100
#define VDIM 10000
#define NV4  2500            // VDIM / 4
#define BLOCK 512
#define NWAVE (BLOCK / 64)   // 8
#define VPT 5                // ceil(NV4 / BLOCK)
#define CHUNK 5
#define NCHUNK (TDIM / CHUNK)

#define INV1 (1.0f / (1.0f + 1e-6f))
#define INVD (1.0f / (0.005f + 1e-6f))
#define LOGD (-5.2983173665480363f)   // log(0.005f)

// native clang vector type: __builtin_nontemporal_* accepts this, and it has
// identical layout/codegen (global_load_dwordx4) to HIP's float4.
typedef float vf4 __attribute__((ext_vector_type(4)));

// guard: jj < VPT-1 rows are always in range (tid + 3*512 <= 2047 < 2500)
#define INRANGE(jj, idx) ((jj) < VPT - 1 || (idx) < NV4)

__device__ __forceinline__ float wave_red_sum(float v) {
#pragma unroll
    for (int m = 32; m >= 1; m >>= 1) v += __shfl_xor(v, m, 64);
    return v;
}

// barrier that does NOT drain vmcnt: stores/loads stay in flight.
// lgkmcnt(0) commits our ds_write of the reduction slot before the barrier.
__device__ __forceinline__ void lds_barrier() {
    asm volatile("s_waitcnt lgkmcnt(0)\n\ts_barrier" ::: "memory");
}

// __launch_bounds__(512, 4): 4 waves/EU minimum -> VGPR cap 128, enough to
// hold the full 15-float4 staging set (60 VGPR) in flight. Deliberately
// trades 8->4 waves/SIMD for ~4x deeper per-wave memory-level parallelism.
__global__ __launch_bounds__(BLOCK, 4) void fused_beta_softmax_kl(
    const float* __restrict__ mu_q,   // [K, T, V]
    const float* __restrict__ lsq,    // [K, T, V]
    const float* __restrict__ eps,    // [T, K, V]
    float* __restrict__ out,          // [T, K, V]
    float* __restrict__ kl)           // scalar (pre-zeroed)
{
    __shared__ vf4 bprev[NV4];        // 40 KB: beta of current row, thread-private slots
    __shared__ float red[2][NWAVE];
    __shared__ float kred[NWAVE];

    const int tid = threadIdx.x;
    const int bid = blockIdx.x;
    const int k   = bid / NCHUNK;
    const int c   = bid % NCHUNK;
    const int t0  = c * CHUNK;
    const int tend = t0 + CHUNK;
    const bool epi = (tend < TDIM);   // this block computes KL term of row tend too

    float klacc = 0.0f;
    vf4 M[VPT], L[VPT], E[VPT];       // staging: 15 loads in flight (60 VGPR)

    for (int t = t0; t < tend; ++t) {
        const size_t po = ((size_t)k * TDIM + t) * VDIM;
        const size_t eo = ((size_t)t * KDIM + k) * VDIM;
        const vf4* m4p = reinterpret_cast<const vf4*>(mu_q + po);
        const vf4* l4p = reinterpret_cast<const vf4*>(lsq + po);
        const vf4* e4p = reinterpret_cast<const vf4*>(eps + eo);
        const bool first = (t == 0);
        const bool skip  = (t == t0) && (t0 != 0);   // prev block owns this KL term

        // ---- stage all 15 global loads back-to-back ----
#pragma unroll
        for (int jj = 0; jj < VPT; ++jj) {
            const int idx = tid + jj * BLOCK;
            if (INRANGE(jj, idx)) {
                M[jj] = m4p[idx];
                L[jj] = l4p[idx];
                E[jj] = __builtin_nontemporal_load(&e4p[idx]);  // pure stream
            }
        }

        // ---- consume: beta -> LDS, KL vs old LDS beta, exp-sum ----
        float lsum = 0.0f;
#pragma unroll
        for (int jj = 0; jj < VPT; ++jj) {
            const int idx = tid + jj * BLOCK;
            if (INRANGE(jj, idx)) {
                const vf4 m = M[jj], l = L[jj], e = E[jj];
                vf4 b;
                b.x = fmaf(__expf(0.5f * l.x), e.x, m.x);
                b.y = fmaf(__expf(0.5f * l.y), e.y, m.y);
                b.z = fmaf(__expf(0.5f * l.z), e.z, m.z);
                b.w = fmaf(__expf(0.5f * l.w), e.w, m.w);
                if (first) {
                    klacc += (__expf(l.x) + m.x * m.x) * INV1 - 1.0f - l.x;
                    klacc += (__expf(l.y) + m.y * m.y) * INV1 - 1.0f - l.y;
                    klacc += (__expf(l.z) + m.z * m.z) * INV1 - 1.0f - l.z;
                    klacc += (__expf(l.w) + m.w * m.w) * INV1 - 1.0f - l.w;
                } else if (!skip) {
                    const vf4 p = bprev[idx];
                    const float dx = m.x - p.x, dy = m.y - p.y,
                                dz = m.z - p.z, dw = m.w - p.w;
                    klacc += (__expf(l.x) + dx * dx) * INVD - 1.0f + LOGD - l.x;
                    klacc += (__expf(l.y) + dy * dy) * INVD - 1.0f + LOGD - l.y;
                    klacc += (__expf(l.z) + dz * dz) * INVD - 1.0f + LOGD - l.z;
                    klacc += (__expf(l.w) + dw * dw) * INVD - 1.0f + LOGD - l.w;
                }
                bprev[idx] = b;
                lsum += __expf(b.x) + __expf(b.y) + __expf(b.z) + __expf(b.w);
            }
        }

        // ---- exp-sum block reduction (vmcnt-preserving barrier) ----
        const int slot = t & 1;
        float ws = wave_red_sum(lsum);
        if ((tid & 63) == 0) red[slot][tid >> 6] = ws;
        lds_barrier();
        float rowsum = 0.0f;
#pragma unroll
        for (int w = 0; w < NWAVE; ++w) rowsum += red[slot][w];
        const float invs = 1.0f / rowsum;

        // ---- write softmax = exp(beta) * invs, beta re-read from LDS ----
        vf4* o4p = reinterpret_cast<vf4*>(out + ((size_t)t * KDIM + k) * VDIM);
#pragma unroll
        for (int jj = 0; jj < VPT; ++jj) {
            const int idx = tid + jj * BLOCK;
            if (INRANGE(jj, idx)) {
                const vf4 b = bprev[idx];
                vf4 o;
                o.x = __expf(b.x) * invs;
                o.y = __expf(b.y) * invs;
                o.z = __expf(b.z) * invs;
                o.w = __expf(b.w) * invs;
                __builtin_nontemporal_store(o, &o4p[idx]);  // streaming output
            }
        }
        // bprev slots are thread-private; red double-buffered -> one barrier/row
    }

    // ---- forward-handoff KL for row tend (mu/lsq only, cache-friendly loads) ----
    if (epi) {
        const size_t po = ((size_t)k * TDIM + tend) * VDIM;
        const vf4* m4p = reinterpret_cast<const vf4*>(mu_q + po);
        const vf4* l4p = reinterpret_cast<const vf4*>(lsq + po);
#pragma unroll
        for (int jj = 0; jj < VPT; ++jj) {
            const int idx = tid + jj * BLOCK;
            if (INRANGE(jj, idx)) { M[jj] = m4p[idx]; L[jj] = l4p[idx]; }
        }
#pragma unroll
        for (int jj = 0; jj < VPT; ++jj) {
            const int idx = tid + jj * BLOCK;
            if (INRANGE(jj, idx)) {
                const vf4 m = M[jj], l = L[jj];
                const vf4 p = bprev[idx];
                const float dx = m.x - p.x, dy = m.y - p.y,
                            dz = m.z - p.z, dw = m.w - p.w;
                klacc += (__expf(l.x) + dx * dx) * INVD - 1.0f + LOGD - l.x;
                klacc += (__expf(l.y) + dy * dy) * INVD - 1.0f + LOGD - l.y;
                klacc += (__expf(l.z) + dz * dz) * INVD - 1.0f + LOGD - l.z;
                klacc += (__expf(l.w) + dw * dw) * INVD - 1.0f + LOGD - l.w;
            }
        }
    }

    // ---- KL block reduction + one atomic per block ----
    float wk = wave_red_sum(klacc);
    __syncthreads();
    if ((tid & 63) == 0) kred[tid >> 6] = wk;
    __syncthreads();
    if (tid == 0) {
        float tot = 0.0f;
#pragma unroll
        for (int w = 0; w < NWAVE; ++w) tot += kred[w];
        atomicAdd(kl, 0.5f * tot);
    }
}

extern "C" void kernel_launch(void* const* d_in, const int* in_sizes, int n_in,
                              void* d_out, int out_size, void* d_ws, size_t ws_size,
                              hipStream_t stream) {
    const float* mu_q = (const float*)d_in[0];  // [K,T,V]
    const float* lsq  = (const float*)d_in[1];  // [K,T,V]
    const float* eps  = (const float*)d_in[2];  // [T,K,V]
    float* out = (float*)d_out;                 // [T,K,V] softmax, then 1 float KL
    float* kl  = out + (size_t)TDIM * KDIM * VDIM;

    // zero the KL accumulator each launch (graph-capture-safe)
    (void)hipMemsetAsync(kl, 0, sizeof(float), stream);

    dim3 grid(KDIM * NCHUNK);
    fused_beta_softmax_kl<<<grid, BLOCK, 0, stream>>>(mu_q, lsq, eps, out, kl);
}